// Round 1
// baseline (741.464 us; speedup 1.0000x reference)
//
#include <hip/hip_runtime.h>
#include <stdint.h>

#define E_   8
#define CAP  768
#define H_   1024
#define F_   4096
#define T_   4096

typedef __attribute__((ext_vector_type(8))) short          s16x8;
typedef __attribute__((ext_vector_type(4))) float          f32x4;
typedef __attribute__((ext_vector_type(4))) unsigned short u16x4;
typedef __attribute__((ext_vector_type(8))) unsigned short u16x8;

__device__ __forceinline__ unsigned short f2bf(float f) {
  uint32_t u = __builtin_bit_cast(uint32_t, f);
  u = u + 0x7fffu + ((u >> 16) & 1u);   // RNE
  return (unsigned short)(u >> 16);
}
__device__ __forceinline__ float bf2f(unsigned short u) {
  uint32_t x = ((uint32_t)u) << 16;
  return __builtin_bit_cast(float, x);
}
__device__ __forceinline__ void async16(const void* g, void* l) {
  __builtin_amdgcn_global_load_lds(
      (const __attribute__((address_space(1))) void*)g,
      (__attribute__((address_space(3))) void*)l, 16, 0, 0);
}

// ---------------- assign: FCFS slot assignment (1 block, 256 threads) ----------
__global__ void assign_kernel(const int* __restrict__ eids, int* __restrict__ tfs,
                              float* __restrict__ valid_out) {
  __shared__ int cnt[256][8];
  const int t = threadIdx.x;
  for (int i = t; i < E_ * CAP; i += 256) tfs[i] = -1;
  int local[8];
#pragma unroll
  for (int e = 0; e < 8; ++e) local[e] = 0;
  const int base = t * 16;
  int myeid[16];
#pragma unroll
  for (int i = 0; i < 16; ++i) {
    int e = eids[base + i];
    e = min(max(e, 0), 7);
    myeid[i] = e;
    local[e]++;
  }
#pragma unroll
  for (int e = 0; e < 8; ++e) cnt[t][e] = local[e];
  __syncthreads();
  if (t < 8) {               // exclusive prefix over chunks, per expert
    int run = 0;
    for (int i = 0; i < 256; ++i) { int v = cnt[i][t]; cnt[i][t] = run; run += v; }
  }
  __syncthreads();
#pragma unroll
  for (int e = 0; e < 8; ++e) local[e] = cnt[t][e];
#pragma unroll
  for (int i = 0; i < 16; ++i) {
    int e = myeid[i];
    int off = local[e]++;
    bool v = off < CAP;
    if (valid_out) valid_out[base + i] = v ? 1.0f : 0.0f;
    if (v) tfs[e * CAP + off] = base + i;
  }
}

// ---------------- zero d_out ----------------
__global__ void zero_kernel(float* __restrict__ p, int n) {
  int i = blockIdx.x * blockDim.x + threadIdx.x;
  const int stride = gridDim.x * blockDim.x;
  for (; i < n; i += stride) p[i] = 0.0f;
}

// ---------------- gather tokens -> bf16 x[E*C, H] ----------------
__global__ void dispatch_x(const float* __restrict__ tokens, const int* __restrict__ tfs,
                           unsigned short* __restrict__ x) {
  const int slot = blockIdx.x;
  const int tok = tfs[slot];
  const int c = threadIdx.x * 4;
  u16x4 o;
  if (tok >= 0) {
    float4 v = *(const float4*)&tokens[(size_t)tok * H_ + c];
    o[0] = f2bf(v.x); o[1] = f2bf(v.y); o[2] = f2bf(v.z); o[3] = f2bf(v.w);
  } else {
    o[0] = o[1] = o[2] = o[3] = 0;
  }
  *(u16x4*)&x[(size_t)slot * H_ + c] = o;
}

// ---------------- transpose + fp32->bf16: out[c][r] = bf16(in[r][c]) ----------
// in: [Z][R][C] fp32 row-major; out: [Z][C][R] bf16 row-major. 64x64 tiles.
__global__ void transpose_cvt(const float* __restrict__ in, unsigned short* __restrict__ out,
                              int R, int C) {
  __shared__ __align__(16) unsigned short tile[64][72];
  const float* ine = in + (size_t)blockIdx.z * R * C;
  unsigned short* oute = out + (size_t)blockIdx.z * R * C;
  const int c0 = blockIdx.x * 64, r0 = blockIdx.y * 64;
  const int tr = threadIdx.x >> 4, tc = threadIdx.x & 15;
#pragma unroll
  for (int i = 0; i < 4; ++i) {
    int r = tr + i * 16;
    float4 v = *(const float4*)&ine[(size_t)(r0 + r) * C + c0 + tc * 4];
    tile[tc * 4 + 0][r] = f2bf(v.x);
    tile[tc * 4 + 1][r] = f2bf(v.y);
    tile[tc * 4 + 2][r] = f2bf(v.z);
    tile[tc * 4 + 3][r] = f2bf(v.w);
  }
  __syncthreads();
  const int ch = threadIdx.x & 7, rr = threadIdx.x >> 3;  // rr 0..31
#pragma unroll
  for (int i = 0; i < 2; ++i) {
    int r = rr + i * 32;
    u16x8 v = *(const u16x8*)&tile[r][ch * 8];
    *(u16x8*)&oute[(size_t)(c0 + r) * R + r0 + ch * 8] = v;
  }
}

// ---------------- swiglu: h = silu(gate) * up, bf16 ----------------
__global__ void swiglu_kernel(const unsigned short* __restrict__ gu,
                              unsigned short* __restrict__ h) {
  const size_t idx = (size_t)blockIdx.x * 256 + threadIdx.x;  // one u16x8 each
  const int row = (int)(idx >> 9);         // 4096/8 = 512 groups per row
  const int col8 = ((int)idx & 511) * 8;
  u16x8 gv = *(const u16x8*)&gu[(size_t)row * (2 * F_) + col8];
  u16x8 uv = *(const u16x8*)&gu[(size_t)row * (2 * F_) + F_ + col8];
  u16x8 o;
#pragma unroll
  for (int j = 0; j < 8; ++j) {
    float g = bf2f(gv[j]);
    float u = bf2f(uv[j]);
    float s = g / (1.0f + __expf(-g));
    o[j] = f2bf(s * u);
  }
  *(u16x8*)&h[(size_t)row * F_ + col8] = o;
}

// ---------------- bf16 GEMM: C[M,N] = A[M,K] * B[K,N], B given transposed (BT[N,K])
// 128x128 tile, BK=64, 4 waves (2x2 of 64x64), 16x16x32 MFMA.
// XOR-swizzled LDS (rule #21: linear LDS dest, pre-swizzled global src, swizzled ds_read).
// EPI 0: store bf16 to outBf (stride N).  EPI 1: scatter fp32 rows via tfs to outF[T_,H_].
template <int EPI>
__global__ __launch_bounds__(256) void gemm_bt(
    const unsigned short* __restrict__ A, const unsigned short* __restrict__ B,
    unsigned short* __restrict__ outBf, float* __restrict__ outF,
    const int* __restrict__ tfs, int N, int K,
    long long aStride, long long bStride, long long oStride) {
  __shared__ __align__(16) unsigned short sA[128 * 64];
  __shared__ __align__(16) unsigned short sB[128 * 64];
  const int e = blockIdx.z;
  const char* Ae = (const char*)(A + (size_t)e * aStride);
  const char* Be = (const char*)(B + (size_t)e * bStride);
  const int rowT0 = blockIdx.y * 128;
  const int colT0 = blockIdx.x * 128;
  const int wave = threadIdx.x >> 6;
  const int lane = threadIdx.x & 63;
  const int wm = wave >> 1, wn = wave & 1;
  const int lrow = lane & 15, kg = lane >> 4;
  const int srow = lane >> 3, sblk0 = lane & 7;
  const int ldb = K * 2;  // bytes per row, both operands K-contiguous

  f32x4 acc[4][4];
#pragma unroll
  for (int m = 0; m < 4; ++m)
#pragma unroll
    for (int n = 0; n < 4; ++n) {
      f32x4 z = {0.f, 0.f, 0.f, 0.f};
      acc[m][n] = z;
    }

  const int nkt = K >> 6;
  for (int kt = 0; kt < nkt; ++kt) {
    const int kByte = kt * 128;
#pragma unroll
    for (int i = 0; i < 4; ++i) {
      const int chunk = i * 4 + wave;          // 16 chunks of 8 rows x 128B
      const int row = chunk * 8 + srow;
      const int sblk = sblk0 ^ (row & 7);      // pre-swizzle global source
      async16(Ae + (size_t)(rowT0 + row) * ldb + kByte + sblk * 16,
              (char*)sA + chunk * 1024);
      async16(Be + (size_t)(colT0 + row) * ldb + kByte + sblk * 16,
              (char*)sB + chunk * 1024);
    }
    __syncthreads();
#pragma unroll
    for (int ks = 0; ks < 2; ++ks) {
      s16x8 af[4], bfr[4];
#pragma unroll
      for (int m = 0; m < 4; ++m) {
        const int row = wm * 64 + m * 16 + lrow;
        const int blk = (ks * 4 + kg) ^ (row & 7);   // swizzled read
        af[m] = *(const s16x8*)((const char*)sA + row * 128 + blk * 16);
      }
#pragma unroll
      for (int n = 0; n < 4; ++n) {
        const int row = wn * 64 + n * 16 + lrow;
        const int blk = (ks * 4 + kg) ^ (row & 7);
        bfr[n] = *(const s16x8*)((const char*)sB + row * 128 + blk * 16);
      }
#pragma unroll
      for (int m = 0; m < 4; ++m)
#pragma unroll
        for (int n = 0; n < 4; ++n)
          acc[m][n] = __builtin_amdgcn_mfma_f32_16x16x32_bf16(af[m], bfr[n], acc[m][n], 0, 0, 0);
    }
    __syncthreads();
  }

  if (EPI == 0) {
    unsigned short* Oe = outBf + (size_t)e * oStride;
#pragma unroll
    for (int m = 0; m < 4; ++m)
#pragma unroll
      for (int j = 0; j < 4; ++j) {
        const int r = rowT0 + wm * 64 + m * 16 + kg * 4 + j;
#pragma unroll
        for (int n = 0; n < 4; ++n) {
          const int c = colT0 + wn * 64 + n * 16 + lrow;
          Oe[(size_t)r * N + c] = f2bf(acc[m][n][j]);
        }
      }
  } else {
    const int* tfse = tfs + e * CAP;
#pragma unroll
    for (int m = 0; m < 4; ++m)
#pragma unroll
      for (int j = 0; j < 4; ++j) {
        const int r = rowT0 + wm * 64 + m * 16 + kg * 4 + j;
        const int tok = tfse[r];
        if (tok >= 0) {
#pragma unroll
          for (int n = 0; n < 4; ++n) {
            const int c = colT0 + wn * 64 + n * 16 + lrow;
            outF[(size_t)tok * H_ + c] = acc[m][n][j];
          }
        }
      }
  }
}

// ---------------- launch ----------------
extern "C" void kernel_launch(void* const* d_in, const int* in_sizes, int n_in,
                              void* d_out, int out_size, void* d_ws, size_t ws_size,
                              hipStream_t stream) {
  const float* tokens = (const float*)d_in[0];
  const int* eids     = (const int*)d_in[1];
  const float* w1     = (const float*)d_in[2];   // [E,H,2F]
  const float* w2     = (const float*)d_in[3];   // [E,F,H]
  float* out = (float*)d_out;

  char* ws = (char*)d_ws;
  int* tfs            = (int*)ws;                                  //   24 KB
  unsigned short* x   = (unsigned short*)(ws + 24576);             // 12.6 MB  [E*C,H]
  unsigned short* w1t = (unsigned short*)(ws + 12607488);          //  134 MB  [E,2F,H]
  unsigned short* w2t = (unsigned short*)(ws + 146825216);         //   67 MB  [E,H,F]
  unsigned short* gu  = (unsigned short*)(ws + 213934080);         //  101 MB  [E*C,2F]
  unsigned short* h   = (unsigned short*)(ws + 314597376);         //   50 MB  [E*C,F]

  float* validp = (out_size >= T_ * H_ + T_) ? out + (size_t)T_ * H_ : nullptr;

  zero_kernel<<<2048, 256, 0, stream>>>(out, out_size);
  assign_kernel<<<1, 256, 0, stream>>>(eids, tfs, validp);
  dispatch_x<<<E_ * CAP, 256, 0, stream>>>(tokens, tfs, x);
  transpose_cvt<<<dim3(2 * F_ / 64, H_ / 64, E_), 256, 0, stream>>>(w1, w1t, H_, 2 * F_);
  transpose_cvt<<<dim3(H_ / 64, F_ / 64, E_), 256, 0, stream>>>(w2, w2t, F_, H_);
  gemm_bt<0><<<dim3(2 * F_ / 128, CAP / 128, E_), 256, 0, stream>>>(
      x, w1t, gu, nullptr, nullptr, 2 * F_, H_,
      (long long)CAP * H_, (long long)2 * F_ * H_, (long long)CAP * 2 * F_);
  swiglu_kernel<<<(E_ * CAP * F_ / 8) / 256, 256, 0, stream>>>(gu, h);
  gemm_bt<1><<<dim3(H_ / 128, CAP / 128, E_), 256, 0, stream>>>(
      h, w2t, nullptr, out, tfs, H_, F_,
      (long long)CAP * F_, (long long)H_ * F_, 0LL);
}

// Round 2
// 710.036 us; speedup vs baseline: 1.0443x; 1.0443x over previous
//
#include <hip/hip_runtime.h>
#include <stdint.h>

#define E_   8
#define CAP  768
#define H_   1024
#define F_   4096
#define T_   4096

typedef __attribute__((ext_vector_type(8))) short          s16x8;
typedef __attribute__((ext_vector_type(4))) float          f32x4;
typedef __attribute__((ext_vector_type(4))) unsigned short u16x4;
typedef __attribute__((ext_vector_type(8))) unsigned short u16x8;

__device__ __forceinline__ unsigned short f2bf(float f) {
  uint32_t u = __builtin_bit_cast(uint32_t, f);
  u = u + 0x7fffu + ((u >> 16) & 1u);   // RNE
  return (unsigned short)(u >> 16);
}
__device__ __forceinline__ float bf2f(unsigned short u) {
  uint32_t x = ((uint32_t)u) << 16;
  return __builtin_bit_cast(float, x);
}
__device__ __forceinline__ void async16(const void* g, void* l) {
  __builtin_amdgcn_global_load_lds(
      (const __attribute__((address_space(1))) void*)g,
      (__attribute__((address_space(3))) void*)l, 16, 0, 0);
}

// ---------------- assign: FCFS slot assignment (1 block, 256 threads) ----------
__global__ void assign_kernel(const int* __restrict__ eids, int* __restrict__ tfs,
                              float* __restrict__ valid_out) {
  __shared__ int cnt[8][256];   // [expert][chunk]
  const int t = threadIdx.x;
  for (int i = t; i < E_ * CAP; i += 256) tfs[i] = -1;
  int local[8];
#pragma unroll
  for (int e = 0; e < 8; ++e) local[e] = 0;
  const int base = t * 16;
  int myeid[16];
#pragma unroll
  for (int i = 0; i < 16; ++i) {
    int e = eids[base + i];
    e = min(max(e, 0), 7);
    myeid[i] = e;
    local[e]++;
  }
#pragma unroll
  for (int e = 0; e < 8; ++e) cnt[e][t] = local[e];
  __syncthreads();
  // wave-parallel exclusive scan over 256 chunks, one expert per wave (4 waves, 2 rounds)
  const int wv = t >> 6, ln = t & 63;
  for (int e = wv; e < 8; e += 4) {
    int v[4], s = 0;
#pragma unroll
    for (int i = 0; i < 4; ++i) { v[i] = cnt[e][ln * 4 + i]; s += v[i]; }
    int inc = s;
#pragma unroll
    for (int d = 1; d < 64; d <<= 1) {
      int o = __shfl_up(inc, d, 64);
      if (ln >= d) inc += o;
    }
    int run = inc - s;   // exclusive prefix of this lane's 4-chunk group
#pragma unroll
    for (int i = 0; i < 4; ++i) { cnt[e][ln * 4 + i] = run; run += v[i]; }
  }
  __syncthreads();
#pragma unroll
  for (int e = 0; e < 8; ++e) local[e] = cnt[e][t];
#pragma unroll
  for (int i = 0; i < 16; ++i) {
    int e = myeid[i];
    int off = local[e]++;
    bool v = off < CAP;
    if (valid_out) valid_out[base + i] = v ? 1.0f : 0.0f;
    if (v) tfs[e * CAP + off] = base + i;
  }
}

// ---------------- zero d_out ----------------
__global__ void zero_kernel(float* __restrict__ p, int n) {
  int i = blockIdx.x * blockDim.x + threadIdx.x;
  const int stride = gridDim.x * blockDim.x;
  for (; i < n; i += stride) p[i] = 0.0f;
}

// ---------------- gather tokens -> bf16 x[E*C, H] ----------------
__global__ void dispatch_x(const float* __restrict__ tokens, const int* __restrict__ tfs,
                           unsigned short* __restrict__ x) {
  const int slot = blockIdx.x;
  const int tok = tfs[slot];
  const int c = threadIdx.x * 4;
  u16x4 o;
  if (tok >= 0) {
    float4 v = *(const float4*)&tokens[(size_t)tok * H_ + c];
    o[0] = f2bf(v.x); o[1] = f2bf(v.y); o[2] = f2bf(v.z); o[3] = f2bf(v.w);
  } else {
    o[0] = o[1] = o[2] = o[3] = 0;
  }
  *(u16x4*)&x[(size_t)slot * H_ + c] = o;
}

// ---------------- transpose + fp32->bf16, conflict-free ----------
// in: [Z][R][C] fp32 row-major; out: [Z][C][R] bf16 row-major (out row = perm(c)).
// PERM=1: gate/up interleave at 16-col granularity: gate c -> (c/16)*32 + c%16,
//         up c (c>=F) -> ((c-F)/16)*32 + 16 + c%16.
// LDS float[64][65]: writes (r + 4tc + i) mod 32 -> 2-way; reads (8g + i + c) -> 2-way. Free.
template <int PERM>
__global__ void transpose_cvt(const float* __restrict__ in, unsigned short* __restrict__ out,
                              int R, int C) {
  __shared__ float tile[64][65];
  const float* ine = in + (size_t)blockIdx.z * R * C;
  unsigned short* oute = out + (size_t)blockIdx.z * (size_t)R * C;
  const int c0 = blockIdx.x * 64, r0 = blockIdx.y * 64;
  const int tr = threadIdx.x >> 4;   // 0..15
  const int tc = threadIdx.x & 15;   // 0..15
#pragma unroll
  for (int i = 0; i < 4; ++i) {
    const int r = tr + i * 16;
    float4 v = *(const float4*)&ine[(size_t)(r0 + r) * C + c0 + tc * 4];
    tile[r][tc * 4 + 0] = v.x;
    tile[r][tc * 4 + 1] = v.y;
    tile[r][tc * 4 + 2] = v.z;
    tile[r][tc * 4 + 3] = v.w;
  }
  __syncthreads();
#pragma unroll
  for (int q = 0; q < 2; ++q) {
    const int task = threadIdx.x + q * 256;
    const int c = task >> 3, g = task & 7;
    u16x8 o;
#pragma unroll
    for (int i = 0; i < 8; ++i) o[i] = f2bf(tile[g * 8 + i][c]);
    const int gc = c0 + c;
    int orow;
    if constexpr (PERM)
      orow = (gc < F_) ? (((gc >> 4) << 5) + (gc & 15))
                       : ((((gc - F_) >> 4) << 5) + 16 + (gc & 15));
    else
      orow = gc;
    *(u16x8*)&oute[(size_t)orow * R + r0 + g * 8] = o;
  }
}

// ---------------- bf16 GEMM: C[M,N] = A[M,K] * B[K,N], B given transposed (BT[N,K])
// 128x128 tile, BK=64, 4 waves (2x2 of 64x64), 16x16x32 MFMA.
// XOR-swizzled LDS (rule #21: linear LDS dest, pre-swizzled global src, swizzled ds_read).
// EPI 1: scatter fp32 rows via tfs to outF[T_,H_].
// EPI 2: fused swiglu -> bf16 h (B columns are gate/up interleaved per 32: n even=gate, odd=up).
template <int EPI>
__global__ __launch_bounds__(256) void gemm_bt(
    const unsigned short* __restrict__ A, const unsigned short* __restrict__ B,
    unsigned short* __restrict__ outBf, float* __restrict__ outF,
    const int* __restrict__ tfs, int N, int K,
    long long aStride, long long bStride, long long oStride) {
  __shared__ __align__(16) unsigned short sA[128 * 64];
  __shared__ __align__(16) unsigned short sB[128 * 64];
  const int e = blockIdx.z;
  const char* Ae = (const char*)(A + (size_t)e * aStride);
  const char* Be = (const char*)(B + (size_t)e * bStride);
  const int rowT0 = blockIdx.y * 128;
  const int colT0 = blockIdx.x * 128;
  const int wave = threadIdx.x >> 6;
  const int lane = threadIdx.x & 63;
  const int wm = wave >> 1, wn = wave & 1;
  const int lrow = lane & 15, kg = lane >> 4;
  const int srow = lane >> 3, sblk0 = lane & 7;
  const int ldb = K * 2;  // bytes per row, both operands K-contiguous

  f32x4 acc[4][4];
#pragma unroll
  for (int m = 0; m < 4; ++m)
#pragma unroll
    for (int n = 0; n < 4; ++n) {
      f32x4 z = {0.f, 0.f, 0.f, 0.f};
      acc[m][n] = z;
    }

  const int nkt = K >> 6;
  for (int kt = 0; kt < nkt; ++kt) {
    const int kByte = kt * 128;
#pragma unroll
    for (int i = 0; i < 4; ++i) {
      const int chunk = i * 4 + wave;          // 16 chunks of 8 rows x 128B
      const int row = chunk * 8 + srow;
      const int sblk = sblk0 ^ (row & 7);      // pre-swizzle global source
      async16(Ae + (size_t)(rowT0 + row) * ldb + kByte + sblk * 16,
              (char*)sA + chunk * 1024);
      async16(Be + (size_t)(colT0 + row) * ldb + kByte + sblk * 16,
              (char*)sB + chunk * 1024);
    }
    __syncthreads();
#pragma unroll
    for (int ks = 0; ks < 2; ++ks) {
      s16x8 af[4], bfr[4];
#pragma unroll
      for (int m = 0; m < 4; ++m) {
        const int row = wm * 64 + m * 16 + lrow;
        const int blk = (ks * 4 + kg) ^ (row & 7);   // swizzled read
        af[m] = *(const s16x8*)((const char*)sA + row * 128 + blk * 16);
      }
#pragma unroll
      for (int n = 0; n < 4; ++n) {
        const int row = wn * 64 + n * 16 + lrow;
        const int blk = (ks * 4 + kg) ^ (row & 7);
        bfr[n] = *(const s16x8*)((const char*)sB + row * 128 + blk * 16);
      }
#pragma unroll
      for (int m = 0; m < 4; ++m)
#pragma unroll
        for (int n = 0; n < 4; ++n)
          acc[m][n] = __builtin_amdgcn_mfma_f32_16x16x32_bf16(af[m], bfr[n], acc[m][n], 0, 0, 0);
    }
    __syncthreads();
  }

  if (EPI == 1) {
    const int* tfse = tfs + e * CAP;
#pragma unroll
    for (int m = 0; m < 4; ++m)
#pragma unroll
      for (int j = 0; j < 4; ++j) {
        const int r = rowT0 + wm * 64 + m * 16 + kg * 4 + j;
        const int tok = tfse[r];
        if (tok >= 0) {
#pragma unroll
          for (int n = 0; n < 4; ++n) {
            const int c = colT0 + wn * 64 + n * 16 + lrow;
            outF[(size_t)tok * H_ + c] = acc[m][n][j];
          }
        }
      }
  } else {  // EPI == 2: fused swiglu, write bf16 h[CAP, F] per expert
    unsigned short* He = outBf + (size_t)e * oStride;
    const int hbase = (colT0 + wn * 64) >> 1;
#pragma unroll
    for (int m = 0; m < 4; ++m)
#pragma unroll
      for (int j = 0; j < 4; ++j) {
        const int r = rowT0 + wm * 64 + m * 16 + kg * 4 + j;
#pragma unroll
        for (int p = 0; p < 2; ++p) {
          float g = acc[m][2 * p][j];
          float u = acc[m][2 * p + 1][j];
          float s = g / (1.0f + __expf(-g));
          He[(size_t)r * F_ + hbase + p * 16 + lrow] = f2bf(s * u);
        }
      }
  }
}

// ---------------- launch ----------------
extern "C" void kernel_launch(void* const* d_in, const int* in_sizes, int n_in,
                              void* d_out, int out_size, void* d_ws, size_t ws_size,
                              hipStream_t stream) {
  const float* tokens = (const float*)d_in[0];
  const int* eids     = (const int*)d_in[1];
  const float* w1     = (const float*)d_in[2];   // [E,H,2F]
  const float* w2     = (const float*)d_in[3];   // [E,F,H]
  float* out = (float*)d_out;

  char* ws = (char*)d_ws;
  int* tfs            = (int*)ws;                                  //   24 KB (pad to 32 KB)
  unsigned short* x   = (unsigned short*)(ws + 32768);             // 12.6 MB  [E*C,H]
  unsigned short* w1t = (unsigned short*)(ws + 32768 + 12582912);  //  134 MB  [E,2F,H] (permuted)
  unsigned short* w2t = (unsigned short*)(ws + 32768 + 12582912 + 134217728);  // 67 MB [E,H,F]
  unsigned short* h   = (unsigned short*)(ws + 32768 + 12582912 + 134217728 + 67108864); // 50 MB [E*C,F]

  float* validp = (out_size >= T_ * H_ + T_) ? out + (size_t)T_ * H_ : nullptr;

  zero_kernel<<<2048, 256, 0, stream>>>(out, out_size);
  assign_kernel<<<1, 256, 0, stream>>>(eids, tfs, validp);
  dispatch_x<<<E_ * CAP, 256, 0, stream>>>(tokens, tfs, x);
  transpose_cvt<1><<<dim3(2 * F_ / 64, H_ / 64, E_), 256, 0, stream>>>(w1, w1t, H_, 2 * F_);
  transpose_cvt<0><<<dim3(H_ / 64, F_ / 64, E_), 256, 0, stream>>>(w2, w2t, F_, H_);
  // GEMM1 + fused swiglu: writes h directly
  gemm_bt<2><<<dim3(2 * F_ / 128, CAP / 128, E_), 256, 0, stream>>>(
      x, w1t, h, nullptr, nullptr, 2 * F_, H_,
      (long long)CAP * H_, (long long)2 * F_ * H_, (long long)CAP * F_);
  // GEMM2 + fused scatter
  gemm_bt<1><<<dim3(H_ / 128, CAP / 128, E_), 256, 0, stream>>>(
      h, w2t, nullptr, out, tfs, H_, F_,
      (long long)CAP * F_, (long long)H_ * F_, 0LL);
}